// Round 2
// baseline (223.281 us; speedup 1.0000x reference)
//
#include <hip/hip_runtime.h>
#include <math.h>

// AdaptiveTripletMarginLoss: B=65536 rows, D=256 fp32.
// R9: revert R8's fusion (device-scope threadfence => buffer_wbl2 L2
// writeback x1024 blocks trashed the read stream: kernel 40 -> 86 us).
// Back to R7's proven two-kernel structure, with ONE change:
//   grid 1024 -> 2048 blocks, 1 group/wave (was 2 via grid-stride).
//   R1 counters: OccupancyPercent ~30%, VGPR=56 <= 64 -> HW allows
//   8 waves/SIMD but the 1024-block grid capped us at 4 blocks/CU.
//   Doubling the grid doubles resident waves -> more outstanding NT
//   loads -> latency-bound stream moves toward the BW floor.
//   __launch_bounds__(256, 8) pins the regalloc at <=64 VGPR.

#define D 256
#define TPB 256
#define ROWS_PER_WAVE 8
#define WAVES_PER_BLOCK 4
#define NBLOCKS 2048

typedef float nt_float4 __attribute__((ext_vector_type(4)));

// lanes with (lane&mask)==0 end holding sum-over-pair of `lo`;
// lanes with (lane&mask)!=0 end holding sum-over-pair of `hi`.
__device__ __forceinline__ float pack_merge(float lo, float hi, int mask, int lane) {
    const bool up = (lane & mask) != 0;
    const float send = up ? lo : hi;          // partner keeps this one
    const float recv = __shfl_xor(send, mask, 64);
    return (up ? hi : lo) + recv;
}

__global__ __launch_bounds__(TPB, 8) void triplet_partial(
    const nt_float4* __restrict__ a4, const nt_float4* __restrict__ p4,
    const nt_float4* __restrict__ n4, float* __restrict__ partial, int B)
{
    const int lane = threadIdx.x & 63;
    const int wib  = threadIdx.x >> 6;
    const int waveId = blockIdx.x * WAVES_PER_BLOCK + wib;
    const int nWaves = NBLOCKS * WAVES_PER_BLOCK;          // 8192
    const int nGroups = B / ROWS_PER_WAVE;                 // 8192

    float local = 0.0f;

    for (int g = waveId; g < nGroups; g += nWaves) {       // exactly 1 iter
        const size_t base = (size_t)g * (ROWS_PER_WAVE * 64) + lane;

        nt_float4 av[ROWS_PER_WAVE], pv[ROWS_PER_WAVE], nv[ROWS_PER_WAVE];
        #pragma unroll
        for (int j = 0; j < ROWS_PER_WAVE; ++j)
            av[j] = __builtin_nontemporal_load(a4 + base + (size_t)j * 64);
        #pragma unroll
        for (int j = 0; j < ROWS_PER_WAVE; ++j)
            pv[j] = __builtin_nontemporal_load(p4 + base + (size_t)j * 64);
        #pragma unroll
        for (int j = 0; j < ROWS_PER_WAVE; ++j)
            nv[j] = __builtin_nontemporal_load(n4 + base + (size_t)j * 64);

        float sap[ROWS_PER_WAVE], san[ROWS_PER_WAVE], spn[ROWS_PER_WAVE];
        #pragma unroll
        for (int j = 0; j < ROWS_PER_WAVE; ++j) {
            float d, s0, s1, s2;
            d = av[j].x - pv[j].x; s0 = d * d;
            d = av[j].y - pv[j].y; s0 = fmaf(d, d, s0);
            d = av[j].z - pv[j].z; s0 = fmaf(d, d, s0);
            d = av[j].w - pv[j].w; s0 = fmaf(d, d, s0);
            d = av[j].x - nv[j].x; s1 = d * d;
            d = av[j].y - nv[j].y; s1 = fmaf(d, d, s1);
            d = av[j].z - nv[j].z; s1 = fmaf(d, d, s1);
            d = av[j].w - nv[j].w; s1 = fmaf(d, d, s1);
            d = pv[j].x - nv[j].x; s2 = d * d;
            d = pv[j].y - nv[j].y; s2 = fmaf(d, d, s2);
            d = pv[j].z - nv[j].z; s2 = fmaf(d, d, s2);
            d = pv[j].w - nv[j].w; s2 = fmaf(d, d, s2);
            sap[j] = s0; san[j] = s1; spn[j] = s2;
        }

        // packing butterfly: 24 -> 12 -> 6 -> 3 values
        float a1[4], n1[4], p1[4];
        #pragma unroll
        for (int r = 0; r < 4; ++r) {           // xor 32: row bit0 <- lane bit5
            a1[r] = pack_merge(sap[2*r], sap[2*r+1], 32, lane);
            n1[r] = pack_merge(san[2*r], san[2*r+1], 32, lane);
            p1[r] = pack_merge(spn[2*r], spn[2*r+1], 32, lane);
        }
        float a2[2], n2[2], p2[2];
        #pragma unroll
        for (int r = 0; r < 2; ++r) {           // xor 16: row bit1 <- lane bit4
            a2[r] = pack_merge(a1[2*r], a1[2*r+1], 16, lane);
            n2[r] = pack_merge(n1[2*r], n1[2*r+1], 16, lane);
            p2[r] = pack_merge(p1[2*r], p1[2*r+1], 16, lane);
        }
        float fa = pack_merge(a2[0], a2[1], 8, lane);   // row bit2 <- lane bit3
        float fn = pack_merge(n2[0], n2[1], 8, lane);
        float fp = pack_merge(p2[0], p2[1], 8, lane);

        // finish within each 8-lane segment (bits 2,1,0)
        fa += __shfl_xor(fa, 4, 64); fa += __shfl_xor(fa, 2, 64); fa += __shfl_xor(fa, 1, 64);
        fn += __shfl_xor(fn, 4, 64); fn += __shfl_xor(fn, 2, 64); fn += __shfl_xor(fn, 1, 64);
        fp += __shfl_xor(fp, 4, 64); fp += __shfl_xor(fp, 2, 64); fp += __shfl_xor(fp, 1, 64);

        // distributed epilogue: every lane holds full sums of ONE row
        // (8 lanes per row -> scale by 1/8)
        const float dap = sqrtf(fa);
        const float dan = sqrtf(fn);
        const float dpn = sqrtf(fp);
        // exp(4*dap) ~ exp(90) -> inf -> term 0 (matches ref fp32)
        const float msim = 1.0f + 2.0f / (__expf(4.0f * dap) + 1e-6f);
        // exp(-4*dan+4) underflows vs 1e-6 -> term ~2e6 (dominates loss)
        const float mdis = 1.0f + 2.0f / (__expf(-4.0f * dan + 4.0f) + 1e-6f);
        local += 0.125f * (dap - 0.5f * (dan + dpn) + msim + mdis);
    }

    // one wave reduce at the end
    #pragma unroll
    for (int off = 32; off >= 1; off >>= 1)
        local += __shfl_xor(local, off, 64);

    __shared__ float sm[WAVES_PER_BLOCK];
    if (lane == 0) sm[wib] = local;
    __syncthreads();
    if (threadIdx.x == 0) {
        float s = 0.0f;
        #pragma unroll
        for (int i = 0; i < WAVES_PER_BLOCK; ++i) s += sm[i];
        partial[blockIdx.x] = s;
    }
}

__global__ __launch_bounds__(256) void final_reduce(
    const float* __restrict__ partial, float* __restrict__ out,
    int nPartial, float invB)
{
    float s = 0.0f;
    for (int i = threadIdx.x; i < nPartial; i += blockDim.x) s += partial[i];
    #pragma unroll
    for (int off = 32; off > 0; off >>= 1) s += __shfl_xor(s, off, 64);

    __shared__ float sm[4];
    const int lane = threadIdx.x & 63;
    const int w = threadIdx.x >> 6;
    if (lane == 0) sm[w] = s;
    __syncthreads();
    if (threadIdx.x == 0) out[0] = (sm[0] + sm[1] + sm[2] + sm[3]) * invB;
}

extern "C" void kernel_launch(void* const* d_in, const int* in_sizes, int n_in,
                              void* d_out, int out_size, void* d_ws, size_t ws_size,
                              hipStream_t stream) {
    const nt_float4* a = (const nt_float4*)d_in[0];
    const nt_float4* p = (const nt_float4*)d_in[1];
    const nt_float4* n = (const nt_float4*)d_in[2];
    float* out = (float*)d_out;
    float* partial = (float*)d_ws;   // NBLOCKS floats (8 KiB) scratch

    const int B = in_sizes[0] / D;   // 65536

    triplet_partial<<<NBLOCKS, TPB, 0, stream>>>(a, p, n, partial, B);
    final_reduce<<<1, 256, 0, stream>>>(partial, out, NBLOCKS, 1.0f / (float)B);
}

// Round 3
// 174.420 us; speedup vs baseline: 1.2801x; 1.2801x over previous
//
#include <hip/hip_runtime.h>
#include <math.h>

// AdaptiveTripletMarginLoss: B=65536 rows, D=256 fp32.
// R10: R7 byte-for-byte (the 175.9us known-good) with ONE change:
//   NBLOCKS 1024 -> 2048 (1 group/wave instead of 2).
// R9's lesson: __launch_bounds__(256,8) forced VGPR 56->32 and spilled
// the 24-float4 load block to scratch (WRITE_SIZE 64KB -> 137MB). So we
// KEEP __launch_bounds__(256,4) -- the compiler's natural 56-VGPR
// allocation fits 8 waves/SIMD in HW anyway; the larger grid is what
// actually raises residency (4096 -> 8192 waves = all wave slots).

#define D 256
#define TPB 256
#define ROWS_PER_WAVE 8
#define WAVES_PER_BLOCK 4
#define NBLOCKS 2048

typedef float nt_float4 __attribute__((ext_vector_type(4)));

// lanes with (lane&mask)==0 end holding sum-over-pair of `lo`;
// lanes with (lane&mask)!=0 end holding sum-over-pair of `hi`.
__device__ __forceinline__ float pack_merge(float lo, float hi, int mask, int lane) {
    const bool up = (lane & mask) != 0;
    const float send = up ? lo : hi;          // partner keeps this one
    const float recv = __shfl_xor(send, mask, 64);
    return (up ? hi : lo) + recv;
}

__global__ __launch_bounds__(TPB, 4) void triplet_partial(
    const nt_float4* __restrict__ a4, const nt_float4* __restrict__ p4,
    const nt_float4* __restrict__ n4, float* __restrict__ partial, int B)
{
    const int lane = threadIdx.x & 63;
    const int wib  = threadIdx.x >> 6;
    const int waveId = blockIdx.x * WAVES_PER_BLOCK + wib;
    const int nWaves = NBLOCKS * WAVES_PER_BLOCK;          // 8192
    const int nGroups = B / ROWS_PER_WAVE;                 // 8192

    float local = 0.0f;

    for (int g = waveId; g < nGroups; g += nWaves) {       // exactly 1 iter
        const size_t base = (size_t)g * (ROWS_PER_WAVE * 64) + lane;

        nt_float4 av[ROWS_PER_WAVE], pv[ROWS_PER_WAVE], nv[ROWS_PER_WAVE];
        #pragma unroll
        for (int j = 0; j < ROWS_PER_WAVE; ++j)
            av[j] = __builtin_nontemporal_load(a4 + base + (size_t)j * 64);
        #pragma unroll
        for (int j = 0; j < ROWS_PER_WAVE; ++j)
            pv[j] = __builtin_nontemporal_load(p4 + base + (size_t)j * 64);
        #pragma unroll
        for (int j = 0; j < ROWS_PER_WAVE; ++j)
            nv[j] = __builtin_nontemporal_load(n4 + base + (size_t)j * 64);

        float sap[ROWS_PER_WAVE], san[ROWS_PER_WAVE], spn[ROWS_PER_WAVE];
        #pragma unroll
        for (int j = 0; j < ROWS_PER_WAVE; ++j) {
            float d, s0, s1, s2;
            d = av[j].x - pv[j].x; s0 = d * d;
            d = av[j].y - pv[j].y; s0 = fmaf(d, d, s0);
            d = av[j].z - pv[j].z; s0 = fmaf(d, d, s0);
            d = av[j].w - pv[j].w; s0 = fmaf(d, d, s0);
            d = av[j].x - nv[j].x; s1 = d * d;
            d = av[j].y - nv[j].y; s1 = fmaf(d, d, s1);
            d = av[j].z - nv[j].z; s1 = fmaf(d, d, s1);
            d = av[j].w - nv[j].w; s1 = fmaf(d, d, s1);
            d = pv[j].x - nv[j].x; s2 = d * d;
            d = pv[j].y - nv[j].y; s2 = fmaf(d, d, s2);
            d = pv[j].z - nv[j].z; s2 = fmaf(d, d, s2);
            d = pv[j].w - nv[j].w; s2 = fmaf(d, d, s2);
            sap[j] = s0; san[j] = s1; spn[j] = s2;
        }

        // packing butterfly: 24 -> 12 -> 6 -> 3 values
        float a1[4], n1[4], p1[4];
        #pragma unroll
        for (int r = 0; r < 4; ++r) {           // xor 32: row bit0 <- lane bit5
            a1[r] = pack_merge(sap[2*r], sap[2*r+1], 32, lane);
            n1[r] = pack_merge(san[2*r], san[2*r+1], 32, lane);
            p1[r] = pack_merge(spn[2*r], spn[2*r+1], 32, lane);
        }
        float a2[2], n2[2], p2[2];
        #pragma unroll
        for (int r = 0; r < 2; ++r) {           // xor 16: row bit1 <- lane bit4
            a2[r] = pack_merge(a1[2*r], a1[2*r+1], 16, lane);
            n2[r] = pack_merge(n1[2*r], n1[2*r+1], 16, lane);
            p2[r] = pack_merge(p1[2*r], p1[2*r+1], 16, lane);
        }
        float fa = pack_merge(a2[0], a2[1], 8, lane);   // row bit2 <- lane bit3
        float fn = pack_merge(n2[0], n2[1], 8, lane);
        float fp = pack_merge(p2[0], p2[1], 8, lane);

        // finish within each 8-lane segment (bits 2,1,0)
        fa += __shfl_xor(fa, 4, 64); fa += __shfl_xor(fa, 2, 64); fa += __shfl_xor(fa, 1, 64);
        fn += __shfl_xor(fn, 4, 64); fn += __shfl_xor(fn, 2, 64); fn += __shfl_xor(fn, 1, 64);
        fp += __shfl_xor(fp, 4, 64); fp += __shfl_xor(fp, 2, 64); fp += __shfl_xor(fp, 1, 64);

        // distributed epilogue: every lane holds full sums of ONE row
        // (8 lanes per row -> scale by 1/8)
        const float dap = sqrtf(fa);
        const float dan = sqrtf(fn);
        const float dpn = sqrtf(fp);
        // exp(4*dap) ~ exp(90) -> inf -> term 0 (matches ref fp32)
        const float msim = 1.0f + 2.0f / (__expf(4.0f * dap) + 1e-6f);
        // exp(-4*dan+4) underflows vs 1e-6 -> term ~2e6 (dominates loss)
        const float mdis = 1.0f + 2.0f / (__expf(-4.0f * dan + 4.0f) + 1e-6f);
        local += 0.125f * (dap - 0.5f * (dan + dpn) + msim + mdis);
    }

    // one wave reduce at the end
    #pragma unroll
    for (int off = 32; off >= 1; off >>= 1)
        local += __shfl_xor(local, off, 64);

    __shared__ float sm[WAVES_PER_BLOCK];
    if (lane == 0) sm[wib] = local;
    __syncthreads();
    if (threadIdx.x == 0) {
        float s = 0.0f;
        #pragma unroll
        for (int i = 0; i < WAVES_PER_BLOCK; ++i) s += sm[i];
        partial[blockIdx.x] = s;
    }
}

__global__ __launch_bounds__(256) void final_reduce(
    const float* __restrict__ partial, float* __restrict__ out,
    int nPartial, float invB)
{
    float s = 0.0f;
    for (int i = threadIdx.x; i < nPartial; i += blockDim.x) s += partial[i];
    #pragma unroll
    for (int off = 32; off > 0; off >>= 1) s += __shfl_xor(s, off, 64);

    __shared__ float sm[4];
    const int lane = threadIdx.x & 63;
    const int w = threadIdx.x >> 6;
    if (lane == 0) sm[w] = s;
    __syncthreads();
    if (threadIdx.x == 0) out[0] = (sm[0] + sm[1] + sm[2] + sm[3]) * invB;
}

extern "C" void kernel_launch(void* const* d_in, const int* in_sizes, int n_in,
                              void* d_out, int out_size, void* d_ws, size_t ws_size,
                              hipStream_t stream) {
    const nt_float4* a = (const nt_float4*)d_in[0];
    const nt_float4* p = (const nt_float4*)d_in[1];
    const nt_float4* n = (const nt_float4*)d_in[2];
    float* out = (float*)d_out;
    float* partial = (float*)d_ws;   // NBLOCKS floats (8 KiB) scratch

    const int B = in_sizes[0] / D;   // 65536

    triplet_partial<<<NBLOCKS, TPB, 0, stream>>>(a, p, n, partial, B);
    final_reduce<<<1, 256, 0, stream>>>(partial, out, NBLOCKS, 1.0f / (float)B);
}